// Round 16
// baseline (497.771 us; speedup 1.0000x reference)
//
#include <hip/hip_runtime.h>
#include <hip/hip_fp16.h>

#define N_NODES 50000
#define N_EDGES 800000
#define D 64
#define NUM_GRAPHS 512
#define FINAL_NEURON 128
#define SCAN_NB ((N_NODES + 255) / 256)   // 196 blocks

// planar fp16 layout: plane p (0/1) holds features [32p, 32p+32) of all nodes.
#define PLANE_U4 ((size_t)N_NODES * 4)
#define PLANE_H2 ((size_t)N_NODES * 16)
#define PLANE_H  ((size_t)N_NODES * 32)

typedef unsigned short ushort_t;

__device__ __forceinline__ float2 h2f(unsigned v) {
    __half2 h = *reinterpret_cast<__half2*>(&v);
    return __half22float2(h);
}

// ---------------- CSR build ----------------
__global__ void k_zero1(int* a, int n) {    // zeroes cnt (N) + dh (256), contiguous
    int i = blockIdx.x * blockDim.x + threadIdx.x;
    if (i < n) a[i] = 0;
}

__global__ void k_hist(const int* __restrict__ dst, int* cnt, ushort_t* __restrict__ epos) {
    int e = blockIdx.x * blockDim.x + threadIdx.x;
    if (e < N_EDGES) epos[e] = (ushort_t)atomicAdd(&cnt[dst[e]], 1);
}

// block sums of cnt; dinv/sdeg; zero g; LDS degree-histogram -> global dh
__global__ void k_blocksum(const int* __restrict__ cnt, int* __restrict__ bsum,
                           float* __restrict__ dinv, float* __restrict__ sdeg,
                           float* __restrict__ g, int* __restrict__ dh) {
    __shared__ int sdata[256];
    __shared__ int lhist[256];
    int t = threadIdx.x;
    int i = blockIdx.x * 256 + t;
    int v = (i < N_NODES) ? cnt[i] : 0;
    lhist[t] = 0;
    if (i < N_NODES) {
        float deg = (float)v + 1.0f;
        dinv[i] = rsqrtf(deg);
        sdeg[i] = sqrtf(deg);
    }
    if (i < NUM_GRAPHS * D) g[i] = 0.f;
    sdata[t] = v;
    __syncthreads();
    if (i < N_NODES) atomicAdd(&lhist[v < 255 ? v : 255], 1);
    for (int s = 128; s > 0; s >>= 1) {
        if (t < s) sdata[t] += sdata[t + s];
        __syncthreads();
    }
    if (t == 0) bsum[blockIdx.x] = sdata[0];
    __syncthreads();
    int c = lhist[t];
    if (c) atomicAdd(&dh[t], c);
}

// single block: scan bsum (196) -> boff; scan dh (256) -> dhoff; init dcur
__global__ void k_scanbsum(const int* __restrict__ bsum, int* __restrict__ boff,
                           const int* __restrict__ dh, int* __restrict__ dhoff,
                           int* __restrict__ dcur) {
    __shared__ int buf[256];
    int t = threadIdx.x;
    int v = (t < SCAN_NB) ? bsum[t] : 0;
    buf[t] = v;
    __syncthreads();
    for (int off = 1; off < 256; off <<= 1) {
        int a = (t >= off) ? buf[t - off] : 0;
        __syncthreads();
        buf[t] += a;
        __syncthreads();
    }
    if (t < SCAN_NB) boff[t] = buf[t] - v;   // exclusive
    __syncthreads();
    int w = dh[t];
    buf[t] = w;
    __syncthreads();
    for (int off = 1; off < 256; off <<= 1) {
        int a = (t >= off) ? buf[t - off] : 0;
        __syncthreads();
        buf[t] += a;
        __syncthreads();
    }
    dhoff[t] = buf[t] - w;                   // exclusive
    dcur[t] = 0;
}

// local scan -> row; plus degree-sorted permutation scatter
__global__ void k_localscan(const int* __restrict__ cnt, const int* __restrict__ boff,
                            int* __restrict__ row, const int* __restrict__ dhoff,
                            int* dcur, int* __restrict__ perm) {
    __shared__ int buf[256];
    int t = threadIdx.x;
    int i = blockIdx.x * 256 + t;
    int v = (i < N_NODES) ? cnt[i] : 0;
    buf[t] = v;
    __syncthreads();
    for (int off = 1; off < 256; off <<= 1) {
        int a = (t >= off) ? buf[t - off] : 0;
        __syncthreads();
        buf[t] += a;
        __syncthreads();
    }
    if (i < N_NODES) {
        row[i] = boff[blockIdx.x] + buf[t] - v;
        int d = v < 255 ? v : 255;
        int pos = atomicAdd(&dcur[d], 1);
        perm[dhoff[d] + pos] = i;
    }
    if (i == 0) row[N_NODES] = N_EDGES;
}

// fused: CSR fill (2B payload) + x -> dinv*x (fp16 planar)
__global__ void k_filltohalf(const int* __restrict__ src, const int* __restrict__ dst,
                             const int* __restrict__ row, const ushort_t* __restrict__ epos,
                             ushort_t* __restrict__ esrc,
                             const float* __restrict__ x, const float* __restrict__ dinv,
                             __half* __restrict__ xh) {
    int i = blockIdx.x * blockDim.x + threadIdx.x;
    if (i < N_EDGES) esrc[row[dst[i]] + (int)epos[i]] = (ushort_t)src[i];
    if (i < N_NODES * 32) {
        float2 f = ((const float2*)x)[i];
        int n = i >> 5, jf = i & 31;
        float s = dinv[n];
        int plane = jf >> 4;
        ((__half2*)xh)[plane * PLANE_H2 + (size_t)n * 16 + (jf & 15)] =
            __floats2half2_rn(f.x * s, f.y * s);
    }
}

// ---------------- gather: agg = dinv .* (A+I) ĥ (planar, degree-sorted) ------
// phase = blockIdx&1 (plane residency); slot -> node via degree-sorted perm:
// waves get equal-degree nodes -> edge-loop iterations ~= mean degree, not max.
__device__ __forceinline__ void acc_add8(float4& a0, float4& a1, uint4 u) {
    float2 p;
    p = h2f(u.x); a0.x += p.x; a0.y += p.y;
    p = h2f(u.y); a0.z += p.x; a0.w += p.y;
    p = h2f(u.z); a1.x += p.x; a1.y += p.y;
    p = h2f(u.w); a1.z += p.x; a1.w += p.y;
}

__global__ __launch_bounds__(256, 8)
void k_gather(const int* __restrict__ row, const ushort_t* __restrict__ esrc,
              const int* __restrict__ perm,
              const __half* __restrict__ hin, const float* __restrict__ dinv,
              __half* __restrict__ agg) {
    int t = threadIdx.x;
    int phase = blockIdx.x & 1;
    int c = t & 3;                        // uint4 within plane-row
    int slot = (blockIdx.x >> 1) * 64 + (t >> 2);
    if (slot >= N_NODES) return;
    int n = perm[slot];

    const uint4* hp = (const uint4*)hin + (size_t)phase * PLANE_U4;
    float4 a0 = {0,0,0,0}, a1 = {0,0,0,0};
    int e = row[n], e1 = row[n + 1];
    for (; e + 4 <= e1; e += 4) {
        int s0 = __builtin_nontemporal_load(esrc + e);
        int s1 = __builtin_nontemporal_load(esrc + e + 1);
        int s2 = __builtin_nontemporal_load(esrc + e + 2);
        int s3 = __builtin_nontemporal_load(esrc + e + 3);
        uint4 u0 = hp[(size_t)s0 * 4 + c];
        uint4 u1 = hp[(size_t)s1 * 4 + c];
        uint4 u2 = hp[(size_t)s2 * 4 + c];
        uint4 u3 = hp[(size_t)s3 * 4 + c];
        acc_add8(a0, a1, u0); acc_add8(a0, a1, u1);
        acc_add8(a0, a1, u2); acc_add8(a0, a1, u3);
    }
    for (; e < e1; ++e) {
        int s = __builtin_nontemporal_load(esrc + e);
        acc_add8(a0, a1, hp[(size_t)s * 4 + c]);
    }
    acc_add8(a0, a1, hp[(size_t)n * 4 + c]);   // self-loop
    float sc = dinv[n];
    __half2 q0 = __floats2half2_rn(a0.x * sc, a0.y * sc);
    __half2 q1 = __floats2half2_rn(a0.z * sc, a0.w * sc);
    __half2 q2 = __floats2half2_rn(a1.x * sc, a1.y * sc);
    __half2 q3 = __floats2half2_rn(a1.z * sc, a1.w * sc);
    uint4 pk = {*(unsigned*)&q0, *(unsigned*)&q1, *(unsigned*)&q2, *(unsigned*)&q3};
    ((uint4*)agg)[(size_t)phase * PLANE_U4 + (size_t)n * 4 + c] = pk;
}

// ---------------- apply: hout = fp16(dinv .* relu(agg @ W + b)), planar ------
__global__ __launch_bounds__(256, 6)
void k_apply(const __half* __restrict__ agg, const float* __restrict__ dinv,
             const float* __restrict__ W, const float* __restrict__ bias,
             __half* __restrict__ hout) {
    __shared__ float4 Ws4[D * 16];       // 16 KB
    __shared__ float  hs[32 * 68];       // 8.7 KB
    int t = threadIdx.x;
    int base = blockIdx.x * 32;

    const float4* W4 = (const float4*)W;
    for (int idx = t; idx < D * 16; idx += 256) Ws4[idx] = W4[idx];

    {   // stage 32 rows: thread t loads one uint4 (8 halves) from planar agg
        int r = t >> 3, q = t & 7;
        int n = base + r;
        int plane = q >> 2, qq = q & 3;
        float4 a0 = {0,0,0,0}, a1 = {0,0,0,0};
        if (n < N_NODES) {
            uint4 u = ((const uint4*)agg)[(size_t)plane * PLANE_U4 + (size_t)n * 4 + qq];
            float2 p;
            p = h2f(u.x); a0.x = p.x; a0.y = p.y;
            p = h2f(u.y); a0.z = p.x; a0.w = p.y;
            p = h2f(u.z); a1.x = p.x; a1.y = p.y;
            p = h2f(u.w); a1.z = p.x; a1.w = p.y;
        }
        int off = plane * 32 + qq * 8;   // feature offset
        *(float4*)&hs[r * 68 + off]     = a0;
        *(float4*)&hs[r * 68 + off + 4] = a1;
    }
    __syncthreads();

    int c = t & 15;
    int rt = (t >> 4) * 2;
    float4 acc0 = {0,0,0,0}, acc1 = {0,0,0,0};
    #pragma unroll 2
    for (int kk = 0; kk < 16; ++kk) {
        float4 h0 = *(const float4*)&hs[(rt + 0) * 68 + kk * 4];
        float4 h1 = *(const float4*)&hs[(rt + 1) * 68 + kk * 4];
        float4 w0 = Ws4[(kk * 4 + 0) * 16 + c];
        float4 w1 = Ws4[(kk * 4 + 1) * 16 + c];
        float4 w2 = Ws4[(kk * 4 + 2) * 16 + c];
        float4 w3 = Ws4[(kk * 4 + 3) * 16 + c];
        acc0.x += h0.x * w0.x + h0.y * w1.x + h0.z * w2.x + h0.w * w3.x;
        acc0.y += h0.x * w0.y + h0.y * w1.y + h0.z * w2.y + h0.w * w3.y;
        acc0.z += h0.x * w0.z + h0.y * w1.z + h0.z * w2.z + h0.w * w3.z;
        acc0.w += h0.x * w0.w + h0.y * w1.w + h0.z * w2.w + h0.w * w3.w;
        acc1.x += h1.x * w0.x + h1.y * w1.x + h1.z * w2.x + h1.w * w3.x;
        acc1.y += h1.x * w0.y + h1.y * w1.y + h1.z * w2.y + h1.w * w3.y;
        acc1.z += h1.x * w0.z + h1.y * w1.z + h1.z * w2.z + h1.w * w3.z;
        acc1.w += h1.x * w0.w + h1.y * w1.w + h1.z * w2.w + h1.w * w3.w;
    }
    float4 bb = ((const float4*)bias)[c];
    int plane = c >> 3;
    size_t oidx = (size_t)plane * ((size_t)N_NODES * 8) + (c & 7);
    int n0 = base + rt, n1 = base + rt + 1;
    if (n0 < N_NODES) {
        float s0 = dinv[n0];
        __half2 lo = __floats2half2_rn(fmaxf(acc0.x + bb.x, 0.f) * s0,
                                       fmaxf(acc0.y + bb.y, 0.f) * s0);
        __half2 hi = __floats2half2_rn(fmaxf(acc0.z + bb.z, 0.f) * s0,
                                       fmaxf(acc0.w + bb.w, 0.f) * s0);
        uint2 pk = {*(unsigned*)&lo, *(unsigned*)&hi};
        ((uint2*)hout)[oidx + (size_t)n0 * 8] = pk;
    }
    if (n1 < N_NODES) {
        float s1 = dinv[n1];
        __half2 lo = __floats2half2_rn(fmaxf(acc1.x + bb.x, 0.f) * s1,
                                       fmaxf(acc1.y + bb.y, 0.f) * s1);
        __half2 hi = __floats2half2_rn(fmaxf(acc1.z + bb.z, 0.f) * s1,
                                       fmaxf(acc1.w + bb.w, 0.f) * s1);
        uint2 pk = {*(unsigned*)&lo, *(unsigned*)&hi};
        ((uint2*)hout)[oidx + (size_t)n1 * 8] = pk;
    }
}

// ---------------- pooling: g += sdeg[n] * ĥ5[n] (planar read) ----------------
__global__ void k_pool(const int* __restrict__ batch, const __half* __restrict__ h,
                       const float* __restrict__ sdeg, float* g) {
    int tid = blockIdx.x * blockDim.x + threadIdx.x;
    int f = tid & 63;
    int n0 = (tid >> 6) * 8;
    if (n0 >= N_NODES) return;
    int n1 = n0 + 8; if (n1 > N_NODES) n1 = N_NODES;
    const __half* hp = h + (size_t)(f >> 5) * PLANE_H + (f & 31);
    int curb = batch[n0];
    float acc = 0.f;
    for (int n = n0; n < n1; ++n) {
        int bb = batch[n];
        if (bb != curb) { atomicAdd(&g[curb * D + f], acc); acc = 0.f; curb = bb; }
        acc += __half2float(hp[(size_t)n * 32]) * sdeg[n];
    }
    atomicAdd(&g[curb * D + f], acc);
}

// ---------------- fused MLP ----------------
__global__ void k_mlp(const float* __restrict__ g, const float* __restrict__ W1,
                      const float* __restrict__ b1, const float* __restrict__ W2,
                      const float* __restrict__ b2, float* __restrict__ out) {
    __shared__ float red[FINAL_NEURON];
    int row = blockIdx.x;
    int j = threadIdx.x;
    float acc = 0.f;
    #pragma unroll
    for (int k = 0; k < D; ++k) acc += g[row * D + k] * W1[k * FINAL_NEURON + j];
    acc = fmaxf(acc + b1[j], 0.f);
    red[j] = acc * W2[j];
    __syncthreads();
    for (int s = 64; s > 0; s >>= 1) {
        if (j < s) red[j] += red[j + s];
        __syncthreads();
    }
    if (j == 0) out[row] = red[0] + b2[0];
}

extern "C" void kernel_launch(void* const* d_in, const int* in_sizes, int n_in,
                              void* d_out, int out_size, void* d_ws, size_t ws_size,
                              hipStream_t stream) {
    const float* x     = (const float*)d_in[0];
    const int*   ei    = (const int*)d_in[1];
    const int*   src   = ei;
    const int*   dst   = ei + N_EDGES;
    const int*   batch = (const int*)d_in[2];
    const float* W[5]  = {(const float*)d_in[3], (const float*)d_in[5], (const float*)d_in[7],
                          (const float*)d_in[9], (const float*)d_in[11]};
    const float* b[5]  = {(const float*)d_in[4], (const float*)d_in[6], (const float*)d_in[8],
                          (const float*)d_in[10], (const float*)d_in[12]};
    const float* fc1W  = (const float*)d_in[13];
    const float* fc1b  = (const float*)d_in[14];
    const float* fc2W  = (const float*)d_in[15];
    const float* fc2b  = (const float*)d_in[16];
    float* out = (float*)d_out;

    __half*   xh   = (__half*)d_ws;                      // N*64 half (planar)
    __half*   agg  = xh + 2 * PLANE_H;                   // N*64 half (planar)
    __half*   hA   = agg + 2 * PLANE_H;                  // N*64 half (planar)
    __half*   hB   = hA + 2 * PLANE_H;                   // N*64 half (planar)
    float*    g    = (float*)(hB + 2 * PLANE_H);         // G*D
    float*    dinv = g + NUM_GRAPHS * D;                 // N
    float*    sdeg = dinv + N_NODES;                     // N
    int*      cnt  = (int*)(sdeg + N_NODES);             // N   (zeroed with dh)
    int*      dh   = cnt + N_NODES;                      // 256 (contiguous w/ cnt)
    int*      row  = dh + 256;                           // N+1
    int*      bsum = row + N_NODES + 1;                  // 256
    int*      boff = bsum + 256;                         // 256
    int*      dhoff= boff + 256;                         // 256
    int*      dcur = dhoff + 256;                        // 256
    int*      perm = dcur + 256;                         // N
    ushort_t* epos = (ushort_t*)(perm + N_NODES);        // E ushort
    ushort_t* esrc = epos + N_EDGES;                     // E ushort

    // ---- CSR build + degree sort + x scaling ----
    k_zero1<<<(N_NODES + 256 + 255) / 256, 256, 0, stream>>>(cnt, N_NODES + 256);
    k_hist<<<(N_EDGES + 255) / 256, 256, 0, stream>>>(dst, cnt, epos);
    k_blocksum<<<SCAN_NB, 256, 0, stream>>>(cnt, bsum, dinv, sdeg, g, dh);
    k_scanbsum<<<1, 256, 0, stream>>>(bsum, boff, dh, dhoff, dcur);
    k_localscan<<<SCAN_NB, 256, 0, stream>>>(cnt, boff, row, dhoff, dcur, perm);
    k_filltohalf<<<(N_NODES * 32 + 255) / 256, 256, 0, stream>>>(src, dst, row, epos, esrc,
                                                                 x, dinv, xh);

    // ---- 5 GCN layers: gather (planar parity, degree-sorted) + apply ----
    const int NG = ((N_NODES + 63) / 64) * 2;   // 2 phases
    const int NA = (N_NODES + 31) / 32;
    k_gather<<<NG, 256, 0, stream>>>(row, esrc, perm, xh, dinv, agg);
    k_apply <<<NA, 256, 0, stream>>>(agg, dinv, W[0], b[0], hA);
    k_gather<<<NG, 256, 0, stream>>>(row, esrc, perm, hA, dinv, agg);
    k_apply <<<NA, 256, 0, stream>>>(agg, dinv, W[1], b[1], hB);
    k_gather<<<NG, 256, 0, stream>>>(row, esrc, perm, hB, dinv, agg);
    k_apply <<<NA, 256, 0, stream>>>(agg, dinv, W[2], b[2], hA);
    k_gather<<<NG, 256, 0, stream>>>(row, esrc, perm, hA, dinv, agg);
    k_apply <<<NA, 256, 0, stream>>>(agg, dinv, W[3], b[3], hB);
    k_gather<<<NG, 256, 0, stream>>>(row, esrc, perm, hB, dinv, agg);
    k_apply <<<NA, 256, 0, stream>>>(agg, dinv, W[4], b[4], hA);

    // ---- readout + fused MLP ----
    k_pool<<<((N_NODES + 7) / 8 * 64 + 255) / 256, 256, 0, stream>>>(batch, hA, sdeg, g);
    k_mlp<<<NUM_GRAPHS, FINAL_NEURON, 0, stream>>>(g, fc1W, fc1b, fc2W, fc2b, out);
}

// Round 17
// 308.920 us; speedup vs baseline: 1.6113x; 1.6113x over previous
//
#include <hip/hip_runtime.h>
#include <hip/hip_fp16.h>

#define N_NODES 50000
#define N_EDGES 800000
#define D 64
#define NUM_GRAPHS 512
#define FINAL_NEURON 128
#define SCAN_NB ((N_NODES + 255) / 256)   // 196 blocks

// planar fp16 layout: plane p (0/1) holds features [32p, 32p+32) of all nodes.
#define PLANE_U4 ((size_t)N_NODES * 4)
#define PLANE_U2 ((size_t)N_NODES * 8)
#define PLANE_H2 ((size_t)N_NODES * 16)
#define PLANE_H  ((size_t)N_NODES * 32)

typedef unsigned short ushort_t;

__device__ __forceinline__ float2 h2f(unsigned v) {
    __half2 h = *reinterpret_cast<__half2*>(&v);
    return __half22float2(h);
}

// ---------------- CSR build ----------------
__global__ void k_zero1(int* a, int n) {
    int i = blockIdx.x * blockDim.x + threadIdx.x;
    if (i < n) a[i] = 0;
}

__global__ void k_hist(const int* __restrict__ dst, int* cnt, ushort_t* __restrict__ epos) {
    int e = blockIdx.x * blockDim.x + threadIdx.x;
    if (e < N_EDGES) epos[e] = (ushort_t)atomicAdd(&cnt[dst[e]], 1);
}

__global__ void k_blocksum(const int* __restrict__ cnt, int* __restrict__ bsum,
                           float* __restrict__ dinv, float* __restrict__ sdeg,
                           float* __restrict__ g) {
    __shared__ int sdata[256];
    int t = threadIdx.x;
    int i = blockIdx.x * 256 + t;
    int v = (i < N_NODES) ? cnt[i] : 0;
    if (i < N_NODES) {
        float deg = (float)v + 1.0f;
        dinv[i] = rsqrtf(deg);
        sdeg[i] = sqrtf(deg);
    }
    if (i < NUM_GRAPHS * D) g[i] = 0.f;
    sdata[t] = v;
    __syncthreads();
    for (int s = 128; s > 0; s >>= 1) {
        if (t < s) sdata[t] += sdata[t + s];
        __syncthreads();
    }
    if (t == 0) bsum[blockIdx.x] = sdata[0];
}

__global__ void k_scanbsum(const int* __restrict__ bsum, int* __restrict__ boff) {
    __shared__ int buf[256];
    int t = threadIdx.x;
    int v = (t < SCAN_NB) ? bsum[t] : 0;
    buf[t] = v;
    __syncthreads();
    for (int off = 1; off < 256; off <<= 1) {
        int a = (t >= off) ? buf[t - off] : 0;
        __syncthreads();
        buf[t] += a;
        __syncthreads();
    }
    if (t < SCAN_NB) boff[t] = buf[t] - v;   // exclusive
}

__global__ void k_localscan(const int* __restrict__ cnt, const int* __restrict__ boff,
                            int* __restrict__ row) {
    __shared__ int buf[256];
    int t = threadIdx.x;
    int i = blockIdx.x * 256 + t;
    int v = (i < N_NODES) ? cnt[i] : 0;
    buf[t] = v;
    __syncthreads();
    for (int off = 1; off < 256; off <<= 1) {
        int a = (t >= off) ? buf[t - off] : 0;
        __syncthreads();
        buf[t] += a;
        __syncthreads();
    }
    if (i < N_NODES) row[i] = boff[blockIdx.x] + buf[t] - v;
    if (i == 0) row[N_NODES] = N_EDGES;
}

// fused: CSR fill (2B payload, rank precomputed -> no atomics) + x -> dinv*x
__global__ void k_filltohalf(const int* __restrict__ src, const int* __restrict__ dst,
                             const int* __restrict__ row, const ushort_t* __restrict__ epos,
                             ushort_t* __restrict__ esrc,
                             const float* __restrict__ x, const float* __restrict__ dinv,
                             __half* __restrict__ xh) {
    int i = blockIdx.x * blockDim.x + threadIdx.x;
    if (i < N_EDGES) esrc[row[dst[i]] + (int)epos[i]] = (ushort_t)src[i];
    if (i < N_NODES * 32) {
        float2 f = ((const float2*)x)[i];
        int n = i >> 5, jf = i & 31;
        float s = dinv[n];
        int plane = jf >> 4;
        ((__half2*)xh)[plane * PLANE_H2 + (size_t)n * 16 + (jf & 15)] =
            __floats2half2_rn(f.x * s, f.y * s);
    }
}

// ---------------- gather: agg = dinv .* (A+I) ĥ (planar, XCD-parity phase) ----
// phase = blockIdx&1: even blocks (even XCDs) stream plane0 (3.2 MB < 4 MB L2),
// odd blocks plane1. 64 nodes x 4 lanes; lane = one uint4 (16B) -> one 64B
// line per edge per phase.
__device__ __forceinline__ void acc_add8(float4& a0, float4& a1, uint4 u) {
    float2 p;
    p = h2f(u.x); a0.x += p.x; a0.y += p.y;
    p = h2f(u.y); a0.z += p.x; a0.w += p.y;
    p = h2f(u.z); a1.x += p.x; a1.y += p.y;
    p = h2f(u.w); a1.z += p.x; a1.w += p.y;
}

__global__ __launch_bounds__(256, 8)
void k_gather(const int* __restrict__ row, const ushort_t* __restrict__ esrc,
              const __half* __restrict__ hin, const float* __restrict__ dinv,
              __half* __restrict__ agg) {
    int t = threadIdx.x;
    int phase = blockIdx.x & 1;
    int c = t & 3;                        // uint4 within plane-row
    int n = (blockIdx.x >> 1) * 64 + (t >> 2);
    if (n >= N_NODES) return;

    const uint4* hp = (const uint4*)hin + (size_t)phase * PLANE_U4;
    float4 a0 = {0,0,0,0}, a1 = {0,0,0,0};
    int e = row[n], e1 = row[n + 1];
    for (; e + 4 <= e1; e += 4) {
        int s0 = __builtin_nontemporal_load(esrc + e);
        int s1 = __builtin_nontemporal_load(esrc + e + 1);
        int s2 = __builtin_nontemporal_load(esrc + e + 2);
        int s3 = __builtin_nontemporal_load(esrc + e + 3);
        uint4 u0 = hp[(size_t)s0 * 4 + c];
        uint4 u1 = hp[(size_t)s1 * 4 + c];
        uint4 u2 = hp[(size_t)s2 * 4 + c];
        uint4 u3 = hp[(size_t)s3 * 4 + c];
        acc_add8(a0, a1, u0); acc_add8(a0, a1, u1);
        acc_add8(a0, a1, u2); acc_add8(a0, a1, u3);
    }
    for (; e < e1; ++e) {
        int s = __builtin_nontemporal_load(esrc + e);
        acc_add8(a0, a1, hp[(size_t)s * 4 + c]);
    }
    acc_add8(a0, a1, hp[(size_t)n * 4 + c]);   // self-loop
    float sc = dinv[n];
    __half2 q0 = __floats2half2_rn(a0.x * sc, a0.y * sc);
    __half2 q1 = __floats2half2_rn(a0.z * sc, a0.w * sc);
    __half2 q2 = __floats2half2_rn(a1.x * sc, a1.y * sc);
    __half2 q3 = __floats2half2_rn(a1.z * sc, a1.w * sc);
    uint4 pk = {*(unsigned*)&q0, *(unsigned*)&q1, *(unsigned*)&q2, *(unsigned*)&q3};
    ((uint4*)agg)[(size_t)phase * PLANE_U4 + (size_t)n * 4 + c] = pk;
}

// ---------------- apply: hout = fp16(dinv .* relu(agg @ W + b)), planar ------
__global__ __launch_bounds__(256, 6)
void k_apply(const __half* __restrict__ agg, const float* __restrict__ dinv,
             const float* __restrict__ W, const float* __restrict__ bias,
             __half* __restrict__ hout) {
    __shared__ float4 Ws4[D * 16];       // 16 KB
    __shared__ float  hs[32 * 68];       // 8.7 KB
    int t = threadIdx.x;
    int base = blockIdx.x * 32;

    const float4* W4 = (const float4*)W;
    for (int idx = t; idx < D * 16; idx += 256) Ws4[idx] = W4[idx];

    {   // stage 32 rows: thread t loads one uint4 (8 halves) from planar agg
        int r = t >> 3, q = t & 7;
        int n = base + r;
        int plane = q >> 2, qq = q & 3;
        float4 a0 = {0,0,0,0}, a1 = {0,0,0,0};
        if (n < N_NODES) {
            uint4 u = ((const uint4*)agg)[(size_t)plane * PLANE_U4 + (size_t)n * 4 + qq];
            float2 p;
            p = h2f(u.x); a0.x = p.x; a0.y = p.y;
            p = h2f(u.y); a0.z = p.x; a0.w = p.y;
            p = h2f(u.z); a1.x = p.x; a1.y = p.y;
            p = h2f(u.w); a1.z = p.x; a1.w = p.y;
        }
        int off = plane * 32 + qq * 8;   // feature offset
        *(float4*)&hs[r * 68 + off]     = a0;
        *(float4*)&hs[r * 68 + off + 4] = a1;
    }
    __syncthreads();

    int c = t & 15;
    int rt = (t >> 4) * 2;
    float4 acc0 = {0,0,0,0}, acc1 = {0,0,0,0};
    #pragma unroll 2
    for (int kk = 0; kk < 16; ++kk) {
        float4 h0 = *(const float4*)&hs[(rt + 0) * 68 + kk * 4];
        float4 h1 = *(const float4*)&hs[(rt + 1) * 68 + kk * 4];
        float4 w0 = Ws4[(kk * 4 + 0) * 16 + c];
        float4 w1 = Ws4[(kk * 4 + 1) * 16 + c];
        float4 w2 = Ws4[(kk * 4 + 2) * 16 + c];
        float4 w3 = Ws4[(kk * 4 + 3) * 16 + c];
        acc0.x += h0.x * w0.x + h0.y * w1.x + h0.z * w2.x + h0.w * w3.x;
        acc0.y += h0.x * w0.y + h0.y * w1.y + h0.z * w2.y + h0.w * w3.y;
        acc0.z += h0.x * w0.z + h0.y * w1.z + h0.z * w2.z + h0.w * w3.z;
        acc0.w += h0.x * w0.w + h0.y * w1.w + h0.z * w2.w + h0.w * w3.w;
        acc1.x += h1.x * w0.x + h1.y * w1.x + h1.z * w2.x + h1.w * w3.x;
        acc1.y += h1.x * w0.y + h1.y * w1.y + h1.z * w2.y + h1.w * w3.y;
        acc1.z += h1.x * w0.z + h1.y * w1.z + h1.z * w2.z + h1.w * w3.z;
        acc1.w += h1.x * w0.w + h1.y * w1.w + h1.z * w2.w + h1.w * w3.w;
    }
    float4 bb = ((const float4*)bias)[c];
    int plane = c >> 3;
    size_t oidx = (size_t)plane * PLANE_U2 + (c & 7);
    int n0 = base + rt, n1 = base + rt + 1;
    if (n0 < N_NODES) {
        float s0 = dinv[n0];
        __half2 lo = __floats2half2_rn(fmaxf(acc0.x + bb.x, 0.f) * s0,
                                       fmaxf(acc0.y + bb.y, 0.f) * s0);
        __half2 hi = __floats2half2_rn(fmaxf(acc0.z + bb.z, 0.f) * s0,
                                       fmaxf(acc0.w + bb.w, 0.f) * s0);
        uint2 pk = {*(unsigned*)&lo, *(unsigned*)&hi};
        ((uint2*)hout)[oidx + (size_t)n0 * 8] = pk;
    }
    if (n1 < N_NODES) {
        float s1 = dinv[n1];
        __half2 lo = __floats2half2_rn(fmaxf(acc1.x + bb.x, 0.f) * s1,
                                       fmaxf(acc1.y + bb.y, 0.f) * s1);
        __half2 hi = __floats2half2_rn(fmaxf(acc1.z + bb.z, 0.f) * s1,
                                       fmaxf(acc1.w + bb.w, 0.f) * s1);
        uint2 pk = {*(unsigned*)&lo, *(unsigned*)&hi};
        ((uint2*)hout)[oidx + (size_t)n1 * 8] = pk;
    }
}

// ---------------- pooling: g += sdeg[n] * ĥ5[n] (planar read) ----------------
__global__ void k_pool(const int* __restrict__ batch, const __half* __restrict__ h,
                       const float* __restrict__ sdeg, float* g) {
    int tid = blockIdx.x * blockDim.x + threadIdx.x;
    int f = tid & 63;
    int n0 = (tid >> 6) * 8;
    if (n0 >= N_NODES) return;
    int n1 = n0 + 8; if (n1 > N_NODES) n1 = N_NODES;
    const __half* hp = h + (size_t)(f >> 5) * PLANE_H + (f & 31);
    int curb = batch[n0];
    float acc = 0.f;
    for (int n = n0; n < n1; ++n) {
        int bb = batch[n];
        if (bb != curb) { atomicAdd(&g[curb * D + f], acc); acc = 0.f; curb = bb; }
        acc += __half2float(hp[(size_t)n * 32]) * sdeg[n];
    }
    atomicAdd(&g[curb * D + f], acc);
}

// ---------------- fused MLP ----------------
__global__ void k_mlp(const float* __restrict__ g, const float* __restrict__ W1,
                      const float* __restrict__ b1, const float* __restrict__ W2,
                      const float* __restrict__ b2, float* __restrict__ out) {
    __shared__ float red[FINAL_NEURON];
    int row = blockIdx.x;
    int j = threadIdx.x;
    float acc = 0.f;
    #pragma unroll
    for (int k = 0; k < D; ++k) acc += g[row * D + k] * W1[k * FINAL_NEURON + j];
    acc = fmaxf(acc + b1[j], 0.f);
    red[j] = acc * W2[j];
    __syncthreads();
    for (int s = 64; s > 0; s >>= 1) {
        if (j < s) red[j] += red[j + s];
        __syncthreads();
    }
    if (j == 0) out[row] = red[0] + b2[0];
}

extern "C" void kernel_launch(void* const* d_in, const int* in_sizes, int n_in,
                              void* d_out, int out_size, void* d_ws, size_t ws_size,
                              hipStream_t stream) {
    const float* x     = (const float*)d_in[0];
    const int*   ei    = (const int*)d_in[1];
    const int*   src   = ei;
    const int*   dst   = ei + N_EDGES;
    const int*   batch = (const int*)d_in[2];
    const float* W[5]  = {(const float*)d_in[3], (const float*)d_in[5], (const float*)d_in[7],
                          (const float*)d_in[9], (const float*)d_in[11]};
    const float* b[5]  = {(const float*)d_in[4], (const float*)d_in[6], (const float*)d_in[8],
                          (const float*)d_in[10], (const float*)d_in[12]};
    const float* fc1W  = (const float*)d_in[13];
    const float* fc1b  = (const float*)d_in[14];
    const float* fc2W  = (const float*)d_in[15];
    const float* fc2b  = (const float*)d_in[16];
    float* out = (float*)d_out;

    __half*   xh   = (__half*)d_ws;                      // N*64 half (planar)
    __half*   agg  = xh + 2 * PLANE_H;                   // N*64 half (planar)
    __half*   hA   = agg + 2 * PLANE_H;                  // N*64 half (planar)
    __half*   hB   = hA + 2 * PLANE_H;                   // N*64 half (planar)
    float*    g    = (float*)(hB + 2 * PLANE_H);         // G*D
    float*    dinv = g + NUM_GRAPHS * D;                 // N
    float*    sdeg = dinv + N_NODES;                     // N
    int*      cnt  = (int*)(sdeg + N_NODES);             // N
    int*      row  = cnt + N_NODES;                      // N+1
    int*      bsum = row + N_NODES + 1;                  // 256
    int*      boff = bsum + 256;                         // 256
    ushort_t* epos = (ushort_t*)(boff + 256);            // E ushort
    ushort_t* esrc = epos + N_EDGES;                     // E ushort

    // ---- CSR build + x scaling ----
    k_zero1<<<(N_NODES + 255) / 256, 256, 0, stream>>>(cnt, N_NODES);
    k_hist<<<(N_EDGES + 255) / 256, 256, 0, stream>>>(dst, cnt, epos);
    k_blocksum<<<SCAN_NB, 256, 0, stream>>>(cnt, bsum, dinv, sdeg, g);
    k_scanbsum<<<1, 256, 0, stream>>>(bsum, boff);
    k_localscan<<<SCAN_NB, 256, 0, stream>>>(cnt, boff, row);
    k_filltohalf<<<(N_NODES * 32 + 255) / 256, 256, 0, stream>>>(src, dst, row, epos, esrc,
                                                                 x, dinv, xh);

    // ---- 5 GCN layers: gather (planar parity) + apply ----
    const int NG = ((N_NODES + 63) / 64) * 2;   // 2 phases
    const int NA = (N_NODES + 31) / 32;
    k_gather<<<NG, 256, 0, stream>>>(row, esrc, xh, dinv, agg);
    k_apply <<<NA, 256, 0, stream>>>(agg, dinv, W[0], b[0], hA);
    k_gather<<<NG, 256, 0, stream>>>(row, esrc, hA, dinv, agg);
    k_apply <<<NA, 256, 0, stream>>>(agg, dinv, W[1], b[1], hB);
    k_gather<<<NG, 256, 0, stream>>>(row, esrc, hB, dinv, agg);
    k_apply <<<NA, 256, 0, stream>>>(agg, dinv, W[2], b[2], hA);
    k_gather<<<NG, 256, 0, stream>>>(row, esrc, hA, dinv, agg);
    k_apply <<<NA, 256, 0, stream>>>(agg, dinv, W[3], b[3], hB);
    k_gather<<<NG, 256, 0, stream>>>(row, esrc, hB, dinv, agg);
    k_apply <<<NA, 256, 0, stream>>>(agg, dinv, W[4], b[4], hA);

    // ---- readout + fused MLP ----
    k_pool<<<((N_NODES + 7) / 8 * 64 + 255) / 256, 256, 0, stream>>>(batch, hA, sdeg, g);
    k_mlp<<<NUM_GRAPHS, FINAL_NEURON, 0, stream>>>(g, fc1W, fc1b, fc2W, fc2b, out);
}